// Round 1
// baseline (594.824 us; speedup 1.0000x reference)
//
#include <hip/hip_runtime.h>
#include <hip/hip_bf16.h>
#include <cstdint>

#define B_ 4
#define N_ 512
#define HID_ 256
#define H_ 8
#define E_ 32
#define T_ 8
#define JC_ 16
#define NCH_ (N_/JC_)
#define SCALE_ 0.17677669529663687f
#define NEG_ (-9.0e15f)

__device__ __forceinline__ void fma4(float4& a, const float4 q, const float4 k) {
  a.x += q.x*k.x; a.y += q.y*k.y; a.z += q.z*k.z; a.w += q.w*k.w;
}

// C[m][n] = scale * (sum_k A[m][k]*W[n][k] + bias[n]);  K = N = 256
__global__ __launch_bounds__(256) void proj_gemm(
    const float* __restrict__ A, const float* __restrict__ W,
    const float* __restrict__ bias, float* __restrict__ C,
    int M, float scale) {
  __shared__ float As[64][36];
  __shared__ float Ws[32][68];   // [kk][n] transposed
  const int tid = threadIdx.x;
  const int tx = tid & 15, ty = tid >> 4;
  const int m0 = blockIdx.x * 64, n0 = blockIdx.y * 64;
  float acc[4][4] = {};
  for (int k0 = 0; k0 < HID_; k0 += 32) {
    #pragma unroll
    for (int o = 0; o < 2; ++o) {
      int u = tid*8 + o*4;
      int r = u >> 5, c = u & 31;
      float4 va = *(const float4*)&A[(size_t)(m0+r)*HID_ + k0 + c];
      *(float4*)&As[r][c] = va;
      float4 vw = *(const float4*)&W[(size_t)(n0+r)*HID_ + k0 + c];
      Ws[c+0][r] = vw.x; Ws[c+1][r] = vw.y; Ws[c+2][r] = vw.z; Ws[c+3][r] = vw.w;
    }
    __syncthreads();
    #pragma unroll
    for (int kk = 0; kk < 32; kk += 4) {
      float ar[4][4], wr[4][4];
      #pragma unroll
      for (int r = 0; r < 4; ++r) *(float4*)ar[r] = *(const float4*)&As[ty*4+r][kk];
      #pragma unroll
      for (int k = 0; k < 4; ++k) *(float4*)wr[k] = *(const float4*)&Ws[kk+k][tx*4];
      #pragma unroll
      for (int r = 0; r < 4; ++r)
        #pragma unroll
        for (int c = 0; c < 4; ++c)
          #pragma unroll
          for (int k = 0; k < 4; ++k)
            acc[r][c] += ar[r][k]*wr[k][c];
    }
    __syncthreads();
  }
  float bv[4];
  *(float4*)bv = *(const float4*)&bias[n0 + tx*4];
  #pragma unroll
  for (int r = 0; r < 4; ++r) {
    float o4[4];
    #pragma unroll
    for (int c = 0; c < 4; ++c) o4[c] = scale*(acc[r][c] + bv[c]);
    *(float4*)&C[(size_t)(m0+ty*4+r)*HID_ + n0 + tx*4] = *(float4*)o4;
  }
}

__global__ __launch_bounds__(256) void fused_graph_attn(
    const float* __restrict__ qhp, const float* __restrict__ khp,
    const float* __restrict__ vhp,
    const float* __restrict__ adj, const float* __restrict__ adj1,
    const float* __restrict__ ef, const float* __restrict__ ab,
    const float* __restrict__ Wap, const float* __restrict__ bap,
    const float* __restrict__ Wep, const float* __restrict__ bep,
    const float* __restrict__ Woe,
    const int* __restrict__ use_adj_p,
    float* __restrict__ y, float* __restrict__ eo)
{
  __shared__ float kh_s[JC_][292];   // (jc, h*36+d)
  __shared__ float vh_s[JC_][292];
  __shared__ float ef_s[JC_][T_][33];
  __shared__ float x_s[T_][H_][17];
  __shared__ float pj_s[JC_][T_][9];
  __shared__ float wg_s[T_][H_][20];
  __shared__ float wl_s[T_][H_][20];
  __shared__ float sg_s[T_][H_];
  __shared__ float sl_s[T_][H_];
  __shared__ float adj_s[T_][17];
  __shared__ float adj1_s[T_][17];
  __shared__ float Wap_s[E_][H_];
  __shared__ float Woe_s[E_][E_];
  __shared__ float Wep_s[H_][E_];
  __shared__ float bap_s[E_];
  __shared__ float bep_s[H_];

  const int tid = threadIdx.x;
  const int b  = blockIdx.x >> 6;
  const int i0 = (blockIdx.x & 63) * T_;
  const int ua = use_adj_p[0];

  for (int u = tid; u < E_*H_; u += 256) Wap_s[u>>3][u&7]   = Wap[u];
  for (int u = tid; u < E_*E_; u += 256) Woe_s[u>>5][u&31]  = Woe[u];
  for (int u = tid; u < H_*E_; u += 256) Wep_s[u>>5][u&31]  = Wep[u];
  if (tid < E_) bap_s[tid] = bap[tid];
  if (tid < H_) bep_s[tid] = bep[tid];
  if (tid < T_*H_) { sg_s[tid>>3][tid&7] = 0.f; sl_s[tid>>3][tid&7] = 0.f; }

  // QK mapping: h, i-pair, jc-pair; persistent qh fragment in regs
  const int hA = tid >> 5;
  const int ip = (tid >> 3) & 3;
  const int jp = tid & 7;
  float4 qh_r[2][8];
  #pragma unroll
  for (int ii = 0; ii < 2; ++ii)
    #pragma unroll
    for (int d4 = 0; d4 < 8; ++d4)
      qh_r[ii][d4] = *(const float4*)&qhp[(size_t)(b*N_ + i0 + ip*2 + ii)*HID_ + hA*32 + d4*4];

  // edge/proj mapping
  const int jc7 = tid >> 4;
  const int il7 = (tid >> 1) & 7;
  const int hf  = tid & 1;
  // softmax-weight mapping
  const int i6 = tid >> 5, h6 = (tid >> 2) & 7, q6 = tid & 3;
  // PV mapping
  const int hh = tid >> 5, dk = tid & 31;

  float accg[T_] = {}, accl[T_] = {};

  for (int ch = 0; ch < NCH_; ++ch) {
    const int j0 = ch * JC_;
    // ---- stage kh, vh, ef, adj tiles ----
    #pragma unroll
    for (int o = 0; o < 4; ++o) {
      int u = tid + o*256;
      int jc = u >> 6, c = (u & 63) * 4;
      float4 kv  = *(const float4*)&khp[(size_t)(b*N_ + j0 + jc)*HID_ + c];
      float4 vv4 = *(const float4*)&vhp[(size_t)(b*N_ + j0 + jc)*HID_ + c];
      int h = c >> 5, d = c & 31;
      *(float4*)&kh_s[jc][h*36 + d] = kv;
      *(float4*)&vh_s[jc][h*36 + d] = vv4;
    }
    #pragma unroll
    for (int o = 0; o < 4; ++o) {
      int u = tid + o*256;
      int jc = u >> 6, r = (u & 63) * 4;
      int il = r >> 5, e0 = r & 31;
      float4 v4 = *(const float4*)&ef[((size_t)(b*N_ + j0 + jc)*N_ + i0 + il)*E_ + e0];
      ef_s[jc][il][e0+0] = v4.x; ef_s[jc][il][e0+1] = v4.y;
      ef_s[jc][il][e0+2] = v4.z; ef_s[jc][il][e0+3] = v4.w;
    }
    {
      int u = tid & 127;
      int il = u >> 4, jc = u & 15;
      if (tid < 128) adj_s [il][jc] = adj [(size_t)(b*N_ + i0 + il)*N_ + j0 + jc];
      else           adj1_s[il][jc] = adj1[(size_t)(b*N_ + i0 + il)*N_ + j0 + jc];
    }
    __syncthreads();

    // ---- QK + adj mask -> x_s ----
    {
      float4 p[2][2];
      #pragma unroll
      for (int a = 0; a < 2; ++a)
        #pragma unroll
        for (int c = 0; c < 2; ++c) p[a][c] = make_float4(0.f,0.f,0.f,0.f);
      #pragma unroll
      for (int d4 = 0; d4 < 8; ++d4) {
        float4 k0 = *(const float4*)&kh_s[jp*2+0][hA*36 + d4*4];
        float4 k1 = *(const float4*)&kh_s[jp*2+1][hA*36 + d4*4];
        fma4(p[0][0], qh_r[0][d4], k0);
        fma4(p[0][1], qh_r[0][d4], k1);
        fma4(p[1][0], qh_r[1][d4], k0);
        fma4(p[1][1], qh_r[1][d4], k1);
      }
      #pragma unroll
      for (int ii = 0; ii < 2; ++ii)
        #pragma unroll
        for (int jj = 0; jj < 2; ++jj) {
          float xv = p[ii][jj].x + p[ii][jj].y + p[ii][jj].z + p[ii][jj].w;
          if (ua) {
            float a = adj_s[ip*2+ii][jp*2+jj];
            xv = (a > 0.f ? xv : NEG_) * a;
          }
          x_s[ip*2+ii][hA][jp*2+jj] = xv;
        }
    }
    // ---- edge_bias projection (Wep) -> pj_s ----
    {
      float ev[32];
      #pragma unroll
      for (int e = 0; e < 32; ++e) ev[e] = ef_s[jc7][il7][e];
      #pragma unroll
      for (int hx = 0; hx < 4; ++hx) {
        int h = hf*4 + hx;
        float pv = bep_s[h];
        #pragma unroll
        for (int e = 0; e < 32; ++e) pv += ev[e]*Wep_s[h][e];
        pj_s[jc7][il7][h] = pv;
      }
    }
    __syncthreads();

    // ---- edge update part1: ef_s += (x^T Wap + bap)*adj1 ----
    {
      float xv[8];
      #pragma unroll
      for (int h = 0; h < 8; ++h) xv[h] = x_s[il7][h][jc7];
      float a1 = adj1_s[il7][jc7];
      #pragma unroll
      for (int ex = 0; ex < 16; ++ex) {
        int e = hf*16 + ex;
        float xp = bap_s[e];
        #pragma unroll
        for (int h = 0; h < 8; ++h) xp += xv[h]*Wap_s[e][h];
        ef_s[jc7][il7][e] += xp*a1;
      }
    }
    // ---- softmax weights (both branches), no-max exp ----
    {
      float xq[4], pj[4], a1v[4], abv[4];
      *(float4*)abv = *(const float4*)&ab[((size_t)(b*H_ + h6)*N_ + i0 + i6)*N_ + j0 + q6*4];
      #pragma unroll
      for (int jj = 0; jj < 4; ++jj) {
        int jc = q6*4 + jj;
        xq[jj]  = x_s[i6][h6][jc];
        pj[jj]  = pj_s[jc][i6][h6];
        a1v[jj] = adj1_s[i6][jc];
      }
      float wg4[4], wl4[4]; float sgp = 0.f, slp = 0.f;
      #pragma unroll
      for (int jj = 0; jj < 4; ++jj) {
        float eg = __expf(xq[jj]*abv[jj]);
        float el = __expf(xq[jj]*pj[jj]*a1v[jj]);
        wg4[jj] = eg; wl4[jj] = el; sgp += eg; slp += el;
      }
      *(float4*)&wg_s[i6][h6][q6*4] = *(float4*)wg4;
      *(float4*)&wl_s[i6][h6][q6*4] = *(float4*)wl4;
      sgp += __shfl_xor(sgp, 1, 64); sgp += __shfl_xor(sgp, 2, 64);
      slp += __shfl_xor(slp, 1, 64); slp += __shfl_xor(slp, 2, 64);
      if (q6 == 0) { sg_s[i6][h6] += sgp; sl_s[i6][h6] += slp; }
    }
    __syncthreads();

    // ---- edge update part2: (ef+xp) @ Woe^T -> edge_out ----
    {
      float tv[32];
      #pragma unroll
      for (int e = 0; e < 32; ++e) tv[e] = ef_s[jc7][il7][e];
      size_t base = ((size_t)(b*N_ + j0 + jc7)*N_ + i0 + il7)*E_ + hf*16;
      #pragma unroll
      for (int g = 0; g < 4; ++g) {
        float o4[4];
        #pragma unroll
        for (int c = 0; c < 4; ++c) {
          int ep = hf*16 + g*4 + c;
          float s = 0.f;
          #pragma unroll
          for (int e = 0; e < 32; ++e) s += tv[e]*Woe_s[ep][e];
          o4[c] = s;
        }
        *(float4*)&eo[base + g*4] = *(float4*)o4;
      }
    }
    // ---- PV accumulate (both branches) ----
    {
      float vv[16];
      #pragma unroll
      for (int jc = 0; jc < 16; ++jc) vv[jc] = vh_s[jc][hh*36 + dk];
      #pragma unroll
      for (int i = 0; i < T_; ++i) {
        float wg[16], wl[16];
        #pragma unroll
        for (int g = 0; g < 4; ++g) {
          *(float4*)&wg[g*4] = *(const float4*)&wg_s[i][hh][g*4];
          *(float4*)&wl[g*4] = *(const float4*)&wl_s[i][hh][g*4];
        }
        float ag = accg[i], al = accl[i];
        #pragma unroll
        for (int jc = 0; jc < 16; ++jc) { ag += wg[jc]*vv[jc]; al += wl[jc]*vv[jc]; }
        accg[i] = ag; accl[i] = al;
      }
    }
    __syncthreads();
  }

  // ---- finalize y = accg/sg + accl/sl ----
  #pragma unroll
  for (int i = 0; i < T_; ++i) {
    float yv = accg[i]/sg_s[i][hh] + accl[i]/sl_s[i][hh];
    y[(size_t)(b*N_ + i0 + i)*HID_ + hh*32 + dk] = yv;
  }
}

extern "C" void kernel_launch(void* const* d_in, const int* in_sizes, int n_in,
                              void* d_out, int out_size, void* d_ws, size_t ws_size,
                              hipStream_t stream) {
  const float* q    = (const float*)d_in[0];
  const float* k    = (const float*)d_in[1];
  const float* v    = (const float*)d_in[2];
  const float* adj  = (const float*)d_in[3];
  const float* adj1 = (const float*)d_in[4];
  const float* ef   = (const float*)d_in[5];
  const float* ab   = (const float*)d_in[6];
  const float* Wq   = (const float*)d_in[7];
  const float* bq   = (const float*)d_in[8];
  const float* Wk   = (const float*)d_in[9];
  const float* bk   = (const float*)d_in[10];
  const float* Wv   = (const float*)d_in[11];
  const float* bv   = (const float*)d_in[12];
  const float* Wap  = (const float*)d_in[13];
  const float* bap  = (const float*)d_in[14];
  const float* Wep  = (const float*)d_in[15];
  const float* bep  = (const float*)d_in[16];
  const float* Wo   = (const float*)d_in[17];
  const float* bo   = (const float*)d_in[18];
  const float* Woe  = (const float*)d_in[19];
  const int* use_adj = (const int*)d_in[20];

  float* out = (float*)d_out;
  float* eo  = out + (size_t)B_*N_*HID_;      // edge_out after out
  float* qh  = (float*)d_ws;
  float* kh  = qh + (size_t)B_*N_*HID_;
  float* vh  = kh + (size_t)B_*N_*HID_;
  float* y   = vh + (size_t)B_*N_*HID_;

  dim3 g(32, 4), blk(256);
  proj_gemm<<<g, blk, 0, stream>>>(q, Wq, bq, qh, B_*N_, SCALE_);
  proj_gemm<<<g, blk, 0, stream>>>(k, Wk, bk, kh, B_*N_, 1.f);
  proj_gemm<<<g, blk, 0, stream>>>(v, Wv, bv, vh, B_*N_, 1.f);
  fused_graph_attn<<<dim3(B_*(N_/T_)), blk, 0, stream>>>(
      qh, kh, vh, adj, adj1, ef, ab, Wap, bap, Wep, bep, Woe, use_adj, y, eo);
  proj_gemm<<<g, blk, 0, stream>>>(y, Wo, bo, out, B_*N_, 1.f);
}